// Round 10
// baseline (201.725 us; speedup 1.0000x reference)
//
#include <hip/hip_runtime.h>

// Problem constants
#define B_   16
#define L_   6
#define H_   352
#define W_   704
#define HW_  (H_ * W_)          // 247808
#define NIMG (B_ * L_)          // 96
#define NMASK (NIMG * HW_)      // 23,789,568
#define THRESH 0.01f

// Work decomposition: wave = (img, strip, chunk)
#define NQ     176              // W/4 quads per row
#define NSTRIP 3                // strips of 62 output quads (last: 52)
#define NCHUNK 44
#define CH     8                // output rows per chunk (44*8 = 352)
#define ITEMS  (NIMG * NSTRIP * NCHUNK)   // 12672 waves
#define NBLK   (ITEMS / 4)                // 3168 blocks of 4 waves

// OOB sentinel: sigmoid(-1e30) == 0 exactly -> zero-padded confidence map
#define OOBV  -1.0e30f

typedef float f4 __attribute__((ext_vector_type(4)));

__device__ __forceinline__ float4 sig4max(float4 a, float4 b) {
    float4 c;
    c.x = 1.f / (1.f + __expf(-fmaxf(a.x, b.x)));
    c.y = 1.f / (1.f + __expf(-fmaxf(a.y, b.y)));
    c.z = 1.f / (1.f + __expf(-fmaxf(a.z, b.z)));
    c.w = 1.f / (1.f + __expf(-fmaxf(a.w, b.w)));
    return c;
}

__device__ __forceinline__ void raw_load(const float* __restrict__ xb,
                                         int h, int iq, float4& a, float4& b) {
    if ((unsigned)h < (unsigned)H_ && (unsigned)iq < (unsigned)NQ) {
        const size_t off = (size_t)h * W_ + 4 * iq;
        a = *(const float4*)(xb + off);
        b = *(const float4*)(xb + HW_ + off);
    } else {
        a = make_float4(OOBV, OOBV, OOBV, OOBV);
        b = make_float4(OOBV, OOBV, OOBV, OOBV);
    }
}

__global__ __launch_bounds__(256, 8) void comm_fused_v6(
    const float* __restrict__ x,      // (B,L,2,H,W)
    const float* __restrict__ gw,     // (1,1,5,5)
    float* __restrict__ out_mask,     // (B*L,1,H,W)
    float* __restrict__ rate,         // scalar
    float* __restrict__ sm_m1)        // out + NMASK (= smoothed base - 1, 16B-aligned)
{
    const int wave = threadIdx.x >> 6;
    const int lane = threadIdx.x & 63;
    const int item = blockIdx.x * 4 + wave;

    const int img   = item / (NSTRIP * NCHUNK);
    const int rem   = item % (NSTRIP * NCHUNK);
    const int strip = rem / NCHUNK;
    const int chunk = rem % NCHUNK;

    const int hA = chunk * CH;
    const int iq = strip * 62 - 1 + lane;
    const bool outlane = (lane >= 1) && (lane <= 62) && (iq < NQ);
    const bool lead    = outlane && (iq > 0);

    const float* xb = x + (size_t)img * (2 * HW_);
    float* __restrict__ sm = sm_m1 + 1;            // true smoothed base

    // Exact separable weights: g2d[i][j] == u[i] * hv[j]
    float u[5], hv[5];
    {
        const float g12 = gw[12];
        #pragma unroll
        for (int i = 0; i < 5; ++i) u[i] = gw[i * 5 + 2];
        #pragma unroll
        for (int j = 0; j < 5; ++j) hv[j] = gw[10 + j] / g12;
    }

    // Prologue: 7 row-pair loads issued back-to-back (14 dwordx4 in flight)
    float4 c0, c1, c2, c3;
    float4 q0a, q0b, q1a, q1b, q2a, q2b;
    {
        float4 a0, b0, a1, b1, a2, b2, a3, b3;
        raw_load(xb, hA - 2, iq, a0, b0);
        raw_load(xb, hA - 1, iq, a1, b1);
        raw_load(xb, hA,     iq, a2, b2);
        raw_load(xb, hA + 1, iq, a3, b3);
        raw_load(xb, hA + 2, iq, q0a, q0b);   // pending row h+2
        raw_load(xb, hA + 3, iq, q1a, q1b);   // pending row h+3
        raw_load(xb, hA + 4, iq, q2a, q2b);   // pending row h+4
        c0 = sig4max(a0, b0);
        c1 = sig4max(a1, b1);
        c2 = sig4max(a2, b2);
        c3 = sig4max(a3, b3);
    }

    const bool ego = (img % L_) == 0;
    float cnt = 0.f;

    #pragma unroll
    for (int r = 0; r < CH; ++r) {
        const int h = hA + r;

        // Prefetch raw row h+5 (depth-3) — only rows this chunk actually needs
        float4 q3a, q3b;
        if (r < CH - 3) {                     // wave-uniform branch
            raw_load(xb, h + 5, iq, q3a, q3b);
        } else {
            q3a = make_float4(OOBV, OOBV, OOBV, OOBV);
            q3b = make_float4(OOBV, OOBV, OOBV, OOBV);
        }

        // Finish conf for row h+2 (its loads were issued 3 iterations ago)
        const float4 c4 = sig4max(q0a, q0b);

        // Vertical 5-tap (registers)
        float4 v;
        v.x = u[0] * c0.x; v.y = u[0] * c0.y; v.z = u[0] * c0.z; v.w = u[0] * c0.w;
        v.x = fmaf(u[1], c1.x, v.x); v.y = fmaf(u[1], c1.y, v.y);
        v.z = fmaf(u[1], c1.z, v.z); v.w = fmaf(u[1], c1.w, v.w);
        v.x = fmaf(u[2], c2.x, v.x); v.y = fmaf(u[2], c2.y, v.y);
        v.z = fmaf(u[2], c2.z, v.z); v.w = fmaf(u[2], c2.w, v.w);
        v.x = fmaf(u[3], c3.x, v.x); v.y = fmaf(u[3], c3.y, v.y);
        v.z = fmaf(u[3], c3.z, v.z); v.w = fmaf(u[3], c3.w, v.w);
        v.x = fmaf(u[4], c4.x, v.x); v.y = fmaf(u[4], c4.y, v.y);
        v.z = fmaf(u[4], c4.z, v.z); v.w = fmaf(u[4], c4.w, v.w);

        // Horizontal halo from neighbor lanes
        const float lz = __shfl_up(v.z, 1);
        const float lw = __shfl_up(v.w, 1);
        const float rx = __shfl_down(v.x, 1);
        const float ry = __shfl_down(v.y, 1);

        // Horizontal conv on ALL lanes (lane 0's o3 feeds lane 1's store)
        const float s0[8] = { lz, lw, v.x, v.y, v.z, v.w, rx, ry };
        float o0, o1, o2, o3;
        {
            float a;
            a = hv[0] * s0[0];
            a = fmaf(hv[1], s0[1], a); a = fmaf(hv[2], s0[2], a);
            a = fmaf(hv[3], s0[3], a); a = fmaf(hv[4], s0[4], a);
            o0 = a;
            a = hv[0] * s0[1];
            a = fmaf(hv[1], s0[2], a); a = fmaf(hv[2], s0[3], a);
            a = fmaf(hv[3], s0[4], a); a = fmaf(hv[4], s0[5], a);
            o1 = a;
            a = hv[0] * s0[2];
            a = fmaf(hv[1], s0[3], a); a = fmaf(hv[2], s0[4], a);
            a = fmaf(hv[3], s0[5], a); a = fmaf(hv[4], s0[6], a);
            o2 = a;
            a = hv[0] * s0[3];
            a = fmaf(hv[1], s0[4], a); a = fmaf(hv[2], s0[5], a);
            a = fmaf(hv[3], s0[6], a); a = fmaf(hv[4], s0[7], a);
            o3 = a;
        }
        const float o3l = __shfl_up(o3, 1);   // left neighbor's col 4iq-1 value

        if (outlane) {
            const size_t idx = (size_t)img * HW_ + (size_t)h * W_ + 4 * iq;

            // smoothed: shifted, 16B-aligned nontemporal f4 store
            if (lead) {
                f4 sv = { o3l, o0, o1, o2 };
                __builtin_nontemporal_store(sv, (f4*)(sm_m1 + idx));
            } else {  // iq == 0: cols 0..2 scalar (no col -1 write)
                __builtin_nontemporal_store(o0, sm + idx + 0);
                __builtin_nontemporal_store(o1, sm + idx + 1);
                __builtin_nontemporal_store(o2, sm + idx + 2);
            }
            if (iq == NQ - 1)                 // image last col (703)
                __builtin_nontemporal_store(o3, sm + idx + 3);

            // mask + rate (rate counted PRE-ego force)
            float m0 = (o0 > THRESH) ? 1.f : 0.f;
            float m1 = (o1 > THRESH) ? 1.f : 0.f;
            float m2 = (o2 > THRESH) ? 1.f : 0.f;
            float m3 = (o3 > THRESH) ? 1.f : 0.f;
            cnt += m0 + m1 + m2 + m3;
            f4 mv = ego ? (f4){1.f, 1.f, 1.f, 1.f} : (f4){m0, m1, m2, m3};
            __builtin_nontemporal_store(mv, (f4*)(out_mask + idx));
        }

        // Shift pipelines
        c0 = c1; c1 = c2; c2 = c3; c3 = c4;
        q0a = q1a; q0b = q1b;
        q1a = q2a; q1b = q2b;
        q2a = q3a; q2b = q3b;
    }

    // Per-wave reduce -> one atomic per wave (no LDS, no barriers)
    #pragma unroll
    for (int off = 32; off >= 1; off >>= 1)
        cnt += __shfl_down(cnt, off);
    if (lane == 0)
        atomicAdd(rate, cnt * (1.f / (float)NMASK));
}

extern "C" void kernel_launch(void* const* d_in, const int* in_sizes, int n_in,
                              void* d_out, int out_size, void* d_ws, size_t ws_size,
                              hipStream_t stream) {
    const float* x  = (const float*)d_in[0];
    const float* gw = (const float*)d_in[1];
    float* out      = (float*)d_out;

    float* mask_out = out;               // 23,789,568
    float* rate_out = out + NMASK;       // 1
    float* sm_m1    = out + NMASK;       // smoothed base - 1 (16B-aligned)

    // rate slot overlaps sm_m1[0], which no smoothed store ever touches
    // (lead stores start at idx>=4; scalar path writes sm_m1+1+idx, idx>=0).
    hipMemsetAsync(rate_out, 0, sizeof(float), stream);

    dim3 grid(NBLK, 1, 1);               // 3168 blocks x 256 threads = 12672 waves
    dim3 block(256, 1, 1);
    comm_fused_v6<<<grid, block, 0, stream>>>(x, gw, mask_out, rate_out, sm_m1);
}

// Round 11
// 129.078 us; speedup vs baseline: 1.5628x; 1.5628x over previous
//
#include <hip/hip_runtime.h>

// Problem constants
#define B_   16
#define L_   6
#define H_   352
#define W_   704
#define HW_  (H_ * W_)          // 247808
#define NIMG (B_ * L_)          // 96
#define NMASK (NIMG * HW_)      // 23,789,568
#define THRESH 0.01f

// Work decomposition: wave = (img, chunk of CH full-width rows)
#define NQ     176              // W/4 quads per row
#define CH     8                // rows per wave (44 chunks * 8 = 352)
#define NCHUNK 44
#define ITEMS  (NIMG * NCHUNK)  // 4224 waves
#define NBLK   (ITEMS / 4)      // 1056 blocks of 4 waves

// OOB sentinel: sigmoid(-1e30) == 0 exactly -> zero-padded confidence map
#define OOBV  -1.0e30f

typedef float f4 __attribute__((ext_vector_type(4)));

__device__ __forceinline__ float4 sig4max(float4 a, float4 b) {
    float4 c;
    c.x = 1.f / (1.f + __expf(-fmaxf(a.x, b.x)));
    c.y = 1.f / (1.f + __expf(-fmaxf(a.y, b.y)));
    c.z = 1.f / (1.f + __expf(-fmaxf(a.z, b.z)));
    c.w = 1.f / (1.f + __expf(-fmaxf(a.w, b.w)));
    return c;
}

__device__ __forceinline__ void raw_load(const float* __restrict__ xb,
                                         int h, int iq, float4& a, float4& b) {
    if ((unsigned)h < (unsigned)H_ && (unsigned)iq < (unsigned)NQ) {
        const size_t off = (size_t)h * W_ + 4 * iq;
        a = *(const float4*)(xb + off);
        b = *(const float4*)(xb + HW_ + off);
    } else {
        a = make_float4(OOBV, OOBV, OOBV, OOBV);
        b = make_float4(OOBV, OOBV, OOBV, OOBV);
    }
}

__global__ __launch_bounds__(256, 4) void comm_fused_v7(
    const float* __restrict__ x,      // (B,L,2,H,W)
    const float* __restrict__ gw,     // (1,1,5,5)
    float* __restrict__ out_mask,     // (B*L,1,H,W)
    float* __restrict__ rate,         // scalar
    float* __restrict__ sm_m1)        // out + NMASK (= smoothed base - 1, 16B-aligned)
{
    const int wave = threadIdx.x >> 6;
    const int lane = threadIdx.x & 63;
    const int item = blockIdx.x * 4 + wave;

    const int img   = item / NCHUNK;
    const int chunk = item % NCHUNK;
    const int hA    = chunk * CH;

    const float* xb = x + (size_t)img * (2 * HW_);
    float* __restrict__ sm = sm_m1 + 1;            // true smoothed base

    // Segment quad indices: wave sweeps 3 column segments per row (full width)
    int  iq[3];
    bool outl[3];
    #pragma unroll
    for (int s = 0; s < 3; ++s) {
        iq[s]   = s * 62 - 1 + lane;
        outl[s] = (lane >= 1) && (lane <= 62) && (iq[s] < NQ);
    }

    // Exact separable weights: g2d[i][j] == u[i] * hv[j]
    float u[5], hv[5];
    {
        const float g12 = gw[12];
        #pragma unroll
        for (int i = 0; i < 5; ++i) u[i] = gw[i * 5 + 2];
        #pragma unroll
        for (int j = 0; j < 5; ++j) hv[j] = gw[10 + j] / g12;
    }

    // Rolling conf window (rows h-2..h+1) + raw pending (row h+2), per segment
    float4 c0[3], c1[3], c2[3], c3[3], pa[3], pb[3];
    #pragma unroll
    for (int s = 0; s < 3; ++s) {
        float4 a, b;
        raw_load(xb, hA - 2, iq[s], a, b); c0[s] = sig4max(a, b);
        raw_load(xb, hA - 1, iq[s], a, b); c1[s] = sig4max(a, b);
        raw_load(xb, hA,     iq[s], a, b); c2[s] = sig4max(a, b);
        raw_load(xb, hA + 1, iq[s], a, b); c3[s] = sig4max(a, b);
        raw_load(xb, hA + 2, iq[s], pa[s], pb[s]);
    }

    const bool ego = (img % L_) == 0;
    float cnt = 0.f;

    for (int r = 0; r < CH; ++r) {
        const int h = hA + r;

        // Issue next pending row (h+3) for all 3 segments back-to-back
        float4 na[3], nb[3];
        if (r + 1 < CH) {
            #pragma unroll
            for (int s = 0; s < 3; ++s)
                raw_load(xb, h + 3, iq[s], na[s], nb[s]);
        }

        #pragma unroll
        for (int s = 0; s < 3; ++s) {
            // Finish conf for row h+2
            const float4 c4 = sig4max(pa[s], pb[s]);

            // Vertical 5-tap (registers)
            float4 v;
            v.x = u[0] * c0[s].x; v.y = u[0] * c0[s].y;
            v.z = u[0] * c0[s].z; v.w = u[0] * c0[s].w;
            v.x = fmaf(u[1], c1[s].x, v.x); v.y = fmaf(u[1], c1[s].y, v.y);
            v.z = fmaf(u[1], c1[s].z, v.z); v.w = fmaf(u[1], c1[s].w, v.w);
            v.x = fmaf(u[2], c2[s].x, v.x); v.y = fmaf(u[2], c2[s].y, v.y);
            v.z = fmaf(u[2], c2[s].z, v.z); v.w = fmaf(u[2], c2[s].w, v.w);
            v.x = fmaf(u[3], c3[s].x, v.x); v.y = fmaf(u[3], c3[s].y, v.y);
            v.z = fmaf(u[3], c3[s].z, v.z); v.w = fmaf(u[3], c3[s].w, v.w);
            v.x = fmaf(u[4], c4.x, v.x); v.y = fmaf(u[4], c4.y, v.y);
            v.z = fmaf(u[4], c4.z, v.z); v.w = fmaf(u[4], c4.w, v.w);

            // Horizontal halo from neighbor lanes
            const float lz = __shfl_up(v.z, 1);
            const float lw = __shfl_up(v.w, 1);
            const float rx = __shfl_down(v.x, 1);
            const float ry = __shfl_down(v.y, 1);

            // Horizontal conv on ALL lanes (lane 0's o3 feeds lane 1's store)
            const float s0[8] = { lz, lw, v.x, v.y, v.z, v.w, rx, ry };
            float o0, o1, o2, o3;
            {
                float a;
                a = hv[0] * s0[0];
                a = fmaf(hv[1], s0[1], a); a = fmaf(hv[2], s0[2], a);
                a = fmaf(hv[3], s0[3], a); a = fmaf(hv[4], s0[4], a);
                o0 = a;
                a = hv[0] * s0[1];
                a = fmaf(hv[1], s0[2], a); a = fmaf(hv[2], s0[3], a);
                a = fmaf(hv[3], s0[4], a); a = fmaf(hv[4], s0[5], a);
                o1 = a;
                a = hv[0] * s0[2];
                a = fmaf(hv[1], s0[3], a); a = fmaf(hv[2], s0[4], a);
                a = fmaf(hv[3], s0[5], a); a = fmaf(hv[4], s0[6], a);
                o2 = a;
                a = hv[0] * s0[3];
                a = fmaf(hv[1], s0[4], a); a = fmaf(hv[2], s0[5], a);
                a = fmaf(hv[3], s0[6], a); a = fmaf(hv[4], s0[7], a);
                o3 = a;
            }
            const float o3l = __shfl_up(o3, 1);   // left neighbor's col 4iq-1

            if (outl[s]) {
                const size_t idx = (size_t)img * HW_ + (size_t)h * W_ + 4 * iq[s];

                // smoothed: shifted, 16B-aligned nontemporal f4 store
                if (iq[s] > 0) {
                    f4 sv = { o3l, o0, o1, o2 };
                    __builtin_nontemporal_store(sv, (f4*)(sm_m1 + idx));
                } else {  // quad 0: cols 0..2 scalar (no col -1 write)
                    __builtin_nontemporal_store(o0, sm + idx + 0);
                    __builtin_nontemporal_store(o1, sm + idx + 1);
                    __builtin_nontemporal_store(o2, sm + idx + 2);
                }
                if (iq[s] == NQ - 1)              // image last col (703)
                    __builtin_nontemporal_store(o3, sm + idx + 3);

                // mask + rate (rate counted PRE-ego force)
                float m0 = (o0 > THRESH) ? 1.f : 0.f;
                float m1 = (o1 > THRESH) ? 1.f : 0.f;
                float m2 = (o2 > THRESH) ? 1.f : 0.f;
                float m3 = (o3 > THRESH) ? 1.f : 0.f;
                cnt += m0 + m1 + m2 + m3;
                f4 mv = ego ? (f4){1.f, 1.f, 1.f, 1.f} : (f4){m0, m1, m2, m3};
                __builtin_nontemporal_store(mv, (f4*)(out_mask + idx));
            }

            // Shift window
            c0[s] = c1[s]; c1[s] = c2[s]; c2[s] = c3[s]; c3[s] = c4;
            if (r + 1 < CH) { pa[s] = na[s]; pb[s] = nb[s]; }
        }
    }

    // Per-wave reduce -> one atomic per wave (no LDS, no barriers)
    #pragma unroll
    for (int off = 32; off >= 1; off >>= 1)
        cnt += __shfl_down(cnt, off);
    if (lane == 0)
        atomicAdd(rate, cnt * (1.f / (float)NMASK));
}

extern "C" void kernel_launch(void* const* d_in, const int* in_sizes, int n_in,
                              void* d_out, int out_size, void* d_ws, size_t ws_size,
                              hipStream_t stream) {
    const float* x  = (const float*)d_in[0];
    const float* gw = (const float*)d_in[1];
    float* out      = (float*)d_out;

    float* mask_out = out;               // 23,789,568
    float* rate_out = out + NMASK;       // 1
    float* sm_m1    = out + NMASK;       // smoothed base - 1 (16B-aligned)

    // rate slot overlaps sm_m1[0], which no smoothed store ever touches
    // (f4 stores start at idx>=4; scalar path writes sm_m1+1+idx, idx>=0).
    hipMemsetAsync(rate_out, 0, sizeof(float), stream);

    dim3 grid(NBLK, 1, 1);               // 1056 blocks x 256 threads = 4224 waves
    dim3 block(256, 1, 1);
    comm_fused_v7<<<grid, block, 0, stream>>>(x, gw, mask_out, rate_out, sm_m1);
}